// Round 1
// 288.744 us; speedup vs baseline: 1.0019x; 1.0019x over previous
//
#include <hip/hip_runtime.h>
#include <hip/hip_bf16.h>

// B=8192, N=M=K=2048, H=10.
// Pipeline (5 launches):
//   1) pre_kernel: [col-sum partials] + [row sums of W] + [X -> per-row-scaled
//      2-level int8 split X1,X2 + sx1 row scales]
//   2) nca_update: finish col sums, per-cell MLP, write Wt = new_weight^T (fp32)
//   3) bquant: per-row (=Wn column) 2-level int8 quantize of Wt -> B1,B2,sw1
//   4) i8 MFMA GEMM — NEW: 256x128 tile, 8 waves (4Mx2N, 64x64/wave),
//      triple-buffered LDS (3x48KB), depth-3 prefetch with counted vmcnt(6)
//      (never drained to 0 in the main loop), 4 phases/K-tile each
//      {ds_read || global_load_lds -> barrier -> lgkm0 -> setprio -> 6 MFMA ->
//      barrier}  (T3+T4+T5 per the 8-phase template).
//   5) row softmax (one wave/row), applying sx1[row] on load.

typedef int int4v __attribute__((ext_vector_type(4)));
typedef int int16v __attribute__((ext_vector_type(16)));

#define GK 2048
#define NROWS 2048
#define MCOLS 2048
#define NCHUNK 16

// ---------------- fused pre-pass --------------------------------------------
#define CS_BLOCKS 128
#define RS_BLOCKS 2048
__global__ __launch_bounds__(256) void pre_kernel(
    const float* __restrict__ X, const float* __restrict__ W,
    signed char* __restrict__ X1, signed char* __restrict__ X2,
    float* __restrict__ sx1,
    float* __restrict__ part, float* __restrict__ rowS) {
  const int bid = blockIdx.x;
  const int tid = threadIdx.x;

  if (bid < CS_BLOCKS) {
    int chunk = bid >> 3;                 // 0..15
    int j = (bid & 7) * 256 + tid;        // column
    int i0 = chunk * (NROWS / NCHUNK);
    float s = 0.f;
    for (int i = i0; i < i0 + NROWS / NCHUNK; ++i) s += W[(size_t)i * MCOLS + j];
    part[(size_t)chunk * MCOLS + j] = s;
    return;
  }
  if (bid < CS_BLOCKS + RS_BLOCKS) {
    int row = bid - CS_BLOCKS;
    const float4* p = (const float4*)(W + (size_t)row * MCOLS);
    float4 a = p[tid];
    float4 b = p[tid + 256];
    float v = (a.x + a.y) + (a.z + a.w) + (b.x + b.y) + (b.z + b.w);
    __shared__ float red[256];
    red[tid] = v;
    __syncthreads();
    for (int s = 128; s > 0; s >>= 1) {
      if (tid < s) red[tid] += red[tid + s];
      __syncthreads();
    }
    if (tid == 0) rowS[row] = red[0];
    return;
  }
  // X row quantization: one block per row, 8 elems/thread
  {
    int row = bid - CS_BLOCKS - RS_BLOCKS;
    const float4* xr = (const float4*)(X + (size_t)row * GK);
    float4 a = xr[tid * 2];
    float4 b = xr[tid * 2 + 1];
    float xs[8] = {a.x, a.y, a.z, a.w, b.x, b.y, b.z, b.w};
    float am = 0.f;
#pragma unroll
    for (int i = 0; i < 8; ++i) am = fmaxf(am, fabsf(xs[i]));
    const int lane = tid & 63, wv = tid >> 6;
#pragma unroll
    for (int off = 32; off > 0; off >>= 1)
      am = fmaxf(am, __shfl_xor(am, off));
    __shared__ float wred[4];
    if (lane == 0) wred[wv] = am;
    __syncthreads();
    float amax = fmaxf(fmaxf(wred[0], wred[1]), fmaxf(wred[2], wred[3]));
    float s1 = amax * (1.0f / 127.0f);
    float inv = 127.0f / amax;
    int q1[8], q2[8];
#pragma unroll
    for (int i = 0; i < 8; ++i) {
      q1[i] = (int)rintf(xs[i] * inv);
      float r = xs[i] - (float)q1[i] * s1;
      q2[i] = (int)rintf(r * (254.0f * inv));
    }
    unsigned lo1 = (q1[0] & 255) | ((q1[1] & 255) << 8) | ((q1[2] & 255) << 16) | ((q1[3] & 255) << 24);
    unsigned hi1 = (q1[4] & 255) | ((q1[5] & 255) << 8) | ((q1[6] & 255) << 16) | ((q1[7] & 255) << 24);
    unsigned lo2 = (q2[0] & 255) | ((q2[1] & 255) << 8) | ((q2[2] & 255) << 16) | ((q2[3] & 255) << 24);
    unsigned hi2 = (q2[4] & 255) | ((q2[5] & 255) << 8) | ((q2[6] & 255) << 16) | ((q2[7] & 255) << 24);
    ((uint2*)(X1 + (size_t)row * GK))[tid] = make_uint2(lo1, hi1);
    ((uint2*)(X2 + (size_t)row * GK))[tid] = make_uint2(lo2, hi2);
    if (tid == 0) sx1[row] = s1;
  }
}

// ------- NCA MLP -> new_weight, transposed fp32 out -------------------------
__global__ __launch_bounds__(256) void nca_update_kernel(
    const float* __restrict__ W, const float* __restrict__ part,
    const float* __restrict__ rowS,
    const float* __restrict__ W1, const float* __restrict__ b1,
    const float* __restrict__ W2, const float* __restrict__ b2,
    const float* __restrict__ W3, const float* __restrict__ b3,
    float* __restrict__ Wt) {
  __shared__ float sW1[30], sb1[10], sW2[100], sb2[10], sW3[10], sb3;
  __shared__ float sColS[32];
  __shared__ float cred[NCHUNK][33];
  __shared__ float Tf[32][33];
  const int tid = threadIdx.x;
  const int i0 = blockIdx.y * 32;
  const int j0 = blockIdx.x * 32;

  if (tid < 30) sW1[tid] = W1[tid];
  if (tid < 10) { sb1[tid] = b1[tid]; sb2[tid] = b2[tid]; sW3[tid] = W3[tid]; }
  if (tid >= 32 && tid < 132) sW2[tid - 32] = W2[tid - 32];
  if (tid == 0) sb3 = b3[0];

  {
    int ch = tid >> 5;
    int jl = tid & 31;
    cred[ch][jl]     = part[(size_t)ch * MCOLS + j0 + jl];
    cred[ch + 8][jl] = part[(size_t)(ch + 8) * MCOLS + j0 + jl];
  }
  __syncthreads();
  if (tid < 32) {
    float s = 0.f;
#pragma unroll
    for (int c = 0; c < NCHUNK; ++c) s += cred[c][tid];
    sColS[tid] = s;
  }
  __syncthreads();

  const int r = tid >> 5;
  const int c = tid & 31;

  float w[4], fwd[4], bwd[4];
#pragma unroll
  for (int cell = 0; cell < 4; ++cell) {
    int il = r + 8 * cell;
    float wv = W[(size_t)(i0 + il) * MCOLS + j0 + c];
    w[cell] = wv;
    fwd[cell] = (sColS[c] - wv) * (1.0f / (float)(NROWS - 1));
    bwd[cell] = (rowS[i0 + il] - wv) * (1.0f / (float)(MCOLS - 1));
  }

  float h1[4][10];
#pragma unroll
  for (int o = 0; o < 10; ++o) {
    float w1a = sW1[o], w1b = sW1[10 + o], w1c = sW1[20 + o], bb = sb1[o];
#pragma unroll
    for (int cell = 0; cell < 4; ++cell) {
      float v = fmaf(w[cell], w1a, fmaf(fwd[cell], w1b, fmaf(bwd[cell], w1c, bb)));
      h1[cell][o] = fmaxf(v, 0.f);
    }
  }
  float u[4] = {sb3, sb3, sb3, sb3};
#pragma unroll
  for (int o = 0; o < 10; ++o) {
    float h2[4];
    float bb = sb2[o];
#pragma unroll
    for (int cell = 0; cell < 4; ++cell) h2[cell] = bb;
#pragma unroll
    for (int p = 0; p < 10; ++p) {
      float wv = sW2[p * 10 + o];
#pragma unroll
      for (int cell = 0; cell < 4; ++cell) h2[cell] = fmaf(h1[cell][p], wv, h2[cell]);
    }
    float w3 = sW3[o];
#pragma unroll
    for (int cell = 0; cell < 4; ++cell) u[cell] = fmaf(fmaxf(h2[cell], 0.f), w3, u[cell]);
  }

#pragma unroll
  for (int cell = 0; cell < 4; ++cell) {
    int il = r + 8 * cell;
    Tf[il][c] = w[cell] + u[cell];
  }
  __syncthreads();

  {
    int r2 = tid >> 4;          // 0..15
    int ic = (tid & 15) * 2;    // 0..30
#pragma unroll
    for (int half = 0; half < 2; ++half) {
      int jl = r2 + 16 * half;
      float2 v = make_float2(Tf[ic][jl], Tf[ic + 1][jl]);
      *(float2*)(&Wt[(size_t)(j0 + jl) * NROWS + i0 + ic]) = v;
    }
  }
}

// -------- B quantize: one block per Wt row (= Wn column) --------------------
__global__ __launch_bounds__(256) void bquant_kernel(
    const float* __restrict__ Wt, signed char* __restrict__ B1,
    signed char* __restrict__ B2, float* __restrict__ sw1) {
  const int row = blockIdx.x;
  const int tid = threadIdx.x;
  const float4* wr = (const float4*)(Wt + (size_t)row * GK);
  float4 a = wr[tid * 2];
  float4 b = wr[tid * 2 + 1];
  float xs[8] = {a.x, a.y, a.z, a.w, b.x, b.y, b.z, b.w};
  float am = 0.f;
#pragma unroll
  for (int i = 0; i < 8; ++i) am = fmaxf(am, fabsf(xs[i]));
  const int lane = tid & 63, wv = tid >> 6;
#pragma unroll
  for (int off = 32; off > 0; off >>= 1)
    am = fmaxf(am, __shfl_xor(am, off));
  __shared__ float wred[4];
  if (lane == 0) wred[wv] = am;
  __syncthreads();
  float amax = fmaxf(fmaxf(wred[0], wred[1]), fmaxf(wred[2], wred[3]));
  float s1 = amax * (1.0f / 127.0f);
  float inv = 127.0f / amax;
  int q1[8], q2[8];
#pragma unroll
  for (int i = 0; i < 8; ++i) {
    q1[i] = (int)rintf(xs[i] * inv);
    float r = xs[i] - (float)q1[i] * s1;
    q2[i] = (int)rintf(r * (254.0f * inv));
  }
  unsigned lo1 = (q1[0] & 255) | ((q1[1] & 255) << 8) | ((q1[2] & 255) << 16) | ((q1[3] & 255) << 24);
  unsigned hi1 = (q1[4] & 255) | ((q1[5] & 255) << 8) | ((q1[6] & 255) << 16) | ((q1[7] & 255) << 24);
  unsigned lo2 = (q2[0] & 255) | ((q2[1] & 255) << 8) | ((q2[2] & 255) << 16) | ((q2[3] & 255) << 24);
  unsigned hi2 = (q2[4] & 255) | ((q2[5] & 255) << 8) | ((q2[6] & 255) << 16) | ((q2[7] & 255) << 24);
  ((uint2*)(B1 + (size_t)row * GK))[tid] = make_uint2(lo1, hi1);
  ((uint2*)(B2 + (size_t)row * GK))[tid] = make_uint2(lo2, hi2);
  if (tid == 0) sw1[row] = s1;
}

// ---------------- phase-pipelined 2-level i8 MFMA GEMM ----------------------
// Tile 256x128, BK=64, 8 waves as 4M x 2N (64x64 output per wave).
// LDS buffer (48KB): A1@0(16K) A2@16K(16K) B1@32K(8K) B2@40K(8K); 3 buffers.
// 1KB block = 16 rows x 64B; slot s holds (row=s>>2, chunk=(s&3)^((s>>3)&3));
// staging lane l fetches row (16*wave + (l>>2)), chunk (l&3)^((l>>3)&3) so the
// pre-swizzled GLOBAL source + linear gload_lds dest reproduce the swizzle
// (rule: both-sides-or-neither). Frag read (row rl, chunk c):
// slot = 4*rl + (c ^ ((rl>>1)&3))  -> 8x-balanced over the 8 16B bank-slots.
// Pipeline: depth-3 prefetch; tile kt+2's 6 gloads issued spread over kt's
// phases P1-P3; top-of-iteration waits vmcnt(6) (kt+1's 6 stay in flight).
#define BM 256
#define BN 128
#define BK 64
#define NT (GK / BK)
#define BUFSZ 49152

__device__ __forceinline__ void glds16(const signed char* g, char* l) {
  __builtin_amdgcn_global_load_lds(
      (const __attribute__((address_space(1))) void*)g,
      (__attribute__((address_space(3))) void*)l, 16, 0, 0);
}

#define QUAD(mi, ni)                                                           \
  {                                                                            \
    acc_h[mi][ni] = __builtin_amdgcn_mfma_i32_32x32x32_i8(                     \
        a1f[mi][0], b1f[ni][0], acc_h[mi][ni], 0, 0, 0);                       \
    acc_c[mi][ni] = __builtin_amdgcn_mfma_i32_32x32x32_i8(                     \
        a1f[mi][0], b2f[ni][0], acc_c[mi][ni], 0, 0, 0);                       \
    acc_c[mi][ni] = __builtin_amdgcn_mfma_i32_32x32x32_i8(                     \
        a2f[mi][0], b1f[ni][0], acc_c[mi][ni], 0, 0, 0);                       \
    acc_h[mi][ni] = __builtin_amdgcn_mfma_i32_32x32x32_i8(                     \
        a1f[mi][1], b1f[ni][1], acc_h[mi][ni], 0, 0, 0);                       \
    acc_c[mi][ni] = __builtin_amdgcn_mfma_i32_32x32x32_i8(                     \
        a1f[mi][1], b2f[ni][1], acc_c[mi][ni], 0, 0, 0);                       \
    acc_c[mi][ni] = __builtin_amdgcn_mfma_i32_32x32x32_i8(                     \
        a2f[mi][1], b1f[ni][1], acc_c[mi][ni], 0, 0, 0);                       \
  }

__global__ __launch_bounds__(512, 2) void gemm_kernel(
    const signed char* __restrict__ X1, const signed char* __restrict__ X2,
    const signed char* __restrict__ B1, const signed char* __restrict__ B2,
    const float* __restrict__ sw1, float* __restrict__ C) {
  __shared__ __align__(16) char sL[3 * BUFSZ];  // 144 KB

  const int tid = threadIdx.x;
  const int lane = tid & 63;
  const int wave = tid >> 6;   // 0..7
  const int wr = wave >> 1;    // 0..3 (M)
  const int wc = wave & 1;     // 0..1 (N)

  const int bx = blockIdx.x;   // 0..15
  const int by = blockIdx.y;   // 0..31

  const signed char* A1g = X1 + (size_t)(by * BM) * GK;
  const signed char* A2g = X2 + (size_t)(by * BM) * GK;
  const signed char* B1g = B1 + (size_t)(bx * BN) * GK;
  const signed char* B2g = B2 + (size_t)(bx * BN) * GK;

  // staging: pre-swizzled per-thread global offset; linear LDS dest
  const int srow = lane >> 2;
  const int schk = (lane & 3) ^ ((lane >> 3) & 3);
  const size_t qoff = (size_t)(wave * 16 + srow) * GK + schk * 16;
  const int wds = wave * 1024;  // wave-uniform LDS dest offset

  // read-side swizzled offsets
  const int rl = lane & 15;
  const int bhalf = (lane >> 4) & 1;
  const int kck = lane >> 5;
  int aoff[2][2], boff[2][2];  // [mi|ni][ks], level-1; level-2 = +16384/+8192
#pragma unroll
  for (int mi = 0; mi < 2; ++mi)
#pragma unroll
    for (int ks = 0; ks < 2; ++ks) {
      int c = 2 * ks + kck;
      int slot = 4 * rl + (c ^ ((rl >> 1) & 3));
      aoff[mi][ks] = (wr * 4 + mi * 2 + bhalf) * 1024 + slot * 16;
      boff[mi][ks] = 32768 + (wc * 4 + mi * 2 + bhalf) * 1024 + slot * 16;
    }

  int16v acc_h[2][2], acc_c[2][2];
#pragma unroll
  for (int i = 0; i < 2; ++i)
#pragma unroll
    for (int j = 0; j < 2; ++j)
#pragma unroll
      for (int e = 0; e < 16; ++e) { acc_h[i][j][e] = 0; acc_c[i][j][e] = 0; }

  // prologue: stage tiles 0 and 1 into buffers 0,1 (12 gloads in flight)
#pragma unroll
  for (int t = 0; t < 2; ++t) {
    char* wb = sL + t * BUFSZ;
    const size_t k0 = (size_t)t * BK;
    glds16(A1g + qoff + k0, wb + wds);
    glds16(A1g + qoff + (size_t)128 * GK + k0, wb + 8192 + wds);
    glds16(A2g + qoff + k0, wb + 16384 + wds);
    glds16(A2g + qoff + (size_t)128 * GK + k0, wb + 24576 + wds);
    glds16(B1g + qoff + k0, wb + 32768 + wds);
    glds16(B2g + qoff + k0, wb + 40960 + wds);
  }

  const char* sbuf = sL;            // buffer for tile kt
  char* wbuf = sL + 2 * BUFSZ;      // buffer for tile kt+2

  int4v a1f[2][2], a2f[2][2], b1f[2][2], b2f[2][2];

#pragma unroll 1
  for (int kt = 0; kt < NT; ++kt) {
    // wait for tile kt's 6 loads (kt+1's 6 newest stay in flight)
    if (kt + 1 < NT) asm volatile("s_waitcnt vmcnt(6)" ::: "memory");
    else             asm volatile("s_waitcnt vmcnt(0)" ::: "memory");
    __builtin_amdgcn_s_barrier();   // everyone's tile-kt data landed; also
                                    // all reads of wbuf (tile kt-1) retired

    const size_t k2 = (size_t)(kt + 2) * BK;
    const bool pf = (kt + 2 < NT);

    // ---- P1: read a[0] + b[0]; prefetch A1 halves ----
#pragma unroll
    for (int ks = 0; ks < 2; ++ks) {
      a1f[0][ks] = *(const int4v*)(sbuf + aoff[0][ks]);
      a2f[0][ks] = *(const int4v*)(sbuf + aoff[0][ks] + 16384);
      b1f[0][ks] = *(const int4v*)(sbuf + boff[0][ks]);
      b2f[0][ks] = *(const int4v*)(sbuf + boff[0][ks] + 8192);
    }
    if (pf) {
      glds16(A1g + qoff + k2, wbuf + wds);
      glds16(A1g + qoff + (size_t)128 * GK + k2, wbuf + 8192 + wds);
    }
    __builtin_amdgcn_s_barrier();
    asm volatile("s_waitcnt lgkmcnt(0)" ::: "memory");
    __builtin_amdgcn_s_setprio(1);
    QUAD(0, 0);
    __builtin_amdgcn_s_setprio(0);
    __builtin_amdgcn_s_barrier();

    // ---- P2: read b[1]; prefetch A2 halves ----
#pragma unroll
    for (int ks = 0; ks < 2; ++ks) {
      b1f[1][ks] = *(const int4v*)(sbuf + boff[1][ks]);
      b2f[1][ks] = *(const int4v*)(sbuf + boff[1][ks] + 8192);
    }
    if (pf) {
      glds16(A2g + qoff + k2, wbuf + 16384 + wds);
      glds16(A2g + qoff + (size_t)128 * GK + k2, wbuf + 24576 + wds);
    }
    __builtin_amdgcn_s_barrier();
    asm volatile("s_waitcnt lgkmcnt(0)" ::: "memory");
    __builtin_amdgcn_s_setprio(1);
    QUAD(0, 1);
    __builtin_amdgcn_s_setprio(0);
    __builtin_amdgcn_s_barrier();

    // ---- P3: read a[1]; prefetch B1,B2 ----
#pragma unroll
    for (int ks = 0; ks < 2; ++ks) {
      a1f[1][ks] = *(const int4v*)(sbuf + aoff[1][ks]);
      a2f[1][ks] = *(const int4v*)(sbuf + aoff[1][ks] + 16384);
    }
    if (pf) {
      glds16(B1g + qoff + k2, wbuf + 32768 + wds);
      glds16(B2g + qoff + k2, wbuf + 40960 + wds);
    }
    __builtin_amdgcn_s_barrier();
    asm volatile("s_waitcnt lgkmcnt(0)" ::: "memory");
    __builtin_amdgcn_s_setprio(1);
    QUAD(1, 1);
    __builtin_amdgcn_s_setprio(0);
    __builtin_amdgcn_s_barrier();

    // ---- P4: no reads; compute last quadrant (b[0] held since P1) ----
    __builtin_amdgcn_s_setprio(1);
    QUAD(1, 0);
    __builtin_amdgcn_s_setprio(0);
    // no closing barrier: next iteration's vmcnt+barrier covers it

    sbuf += BUFSZ; if (sbuf == sL + 3 * BUFSZ) sbuf = sL;
    wbuf += BUFSZ; if (wbuf == sL + 3 * BUFSZ) wbuf = sL;
  }

  // epilogue: C/D col=lane&31, row=(reg&3)+8*(reg>>2)+4*(lane>>5); apply sw1
  const int ecol = lane & 31;
  const int erow = 4 * (lane >> 5);
#pragma unroll
  for (int ni = 0; ni < 2; ++ni) {
    int col = bx * BN + wc * 64 + ni * 32 + ecol;
    float sw = sw1[col];
#pragma unroll
    for (int mi = 0; mi < 2; ++mi) {
#pragma unroll
      for (int reg = 0; reg < 16; ++reg) {
        int row = by * BM + wr * 64 + mi * 32 + (reg & 3) + 8 * (reg >> 2) + erow;
        float v = (float)acc_h[mi][ni][reg] + (float)acc_c[mi][ni][reg] * (1.0f / 254.0f);
        C[(size_t)row * MCOLS + col] = v * sw;
      }
    }
  }
}

// ---------------- row softmax: one wave per row, applies sx1[row] -----------
__global__ __launch_bounds__(256) void softmax_kernel(
    float* __restrict__ C, const float* __restrict__ sx1) {
  const int lane = threadIdx.x & 63;
  const int wv = threadIdx.x >> 6;
  const int row = blockIdx.x * 4 + wv;
  const float sx = sx1[row];
  float4* p = (float4*)(C + (size_t)row * MCOLS);

  float4 v[8];
#pragma unroll
  for (int j = 0; j < 8; ++j) {
    v[j] = p[j * 64 + lane];
    v[j].x *= sx; v[j].y *= sx; v[j].z *= sx; v[j].w *= sx;
  }

  float vmax = -3.4e38f;
#pragma unroll
  for (int j = 0; j < 8; ++j)
    vmax = fmaxf(vmax, fmaxf(fmaxf(v[j].x, v[j].y), fmaxf(v[j].z, v[j].w)));
#pragma unroll
  for (int off = 32; off > 0; off >>= 1)
    vmax = fmaxf(vmax, __shfl_xor(vmax, off));

  float sum = 0.f;
#pragma unroll
  for (int j = 0; j < 8; ++j) {
    v[j].x = __expf(v[j].x - vmax);
    v[j].y = __expf(v[j].y - vmax);
    v[j].z = __expf(v[j].z - vmax);
    v[j].w = __expf(v[j].w - vmax);
    sum += (v[j].x + v[j].y) + (v[j].z + v[j].w);
  }
#pragma unroll
  for (int off = 32; off > 0; off >>= 1)
    sum += __shfl_xor(sum, off);
  float inv = 1.0f / sum;

#pragma unroll
  for (int j = 0; j < 8; ++j) {
    v[j].x *= inv; v[j].y *= inv; v[j].z *= inv; v[j].w *= inv;
    p[j * 64 + lane] = v[j];
  }
}

// ---------------- launcher --------------------------------------------------
extern "C" void kernel_launch(void* const* d_in, const int* in_sizes, int n_in,
                              void* d_out, int out_size, void* d_ws, size_t ws_size,
                              hipStream_t stream) {
  const float* X      = (const float*)d_in[0];
  const float* weight = (const float*)d_in[1];
  const float* W1     = (const float*)d_in[2];
  const float* b1     = (const float*)d_in[3];
  const float* W2     = (const float*)d_in[4];
  const float* b2     = (const float*)d_in[5];
  const float* W3     = (const float*)d_in[6];
  const float* b3     = (const float*)d_in[7];
  float* out = (float*)d_out;

  const int N = 2048, M = 2048;
  const int Bdim = in_sizes[0] / N;   // 8192

  float* rowS = (float*)d_ws;
  float* part = rowS + 2048;
  float* sx1  = part + NCHUNK * 2048;
  float* sw1  = sx1 + 8192;
  float* Wt   = sw1 + 2048;
  signed char* X1 = (signed char*)(Wt + (size_t)M * N);
  signed char* X2 = X1 + (size_t)Bdim * N;
  signed char* B1q = X2 + (size_t)Bdim * N;
  signed char* B2q = B1q + (size_t)M * N;

  pre_kernel<<<CS_BLOCKS + RS_BLOCKS + Bdim, 256, 0, stream>>>(
      X, weight, X1, X2, sx1, part, rowS);

  nca_update_kernel<<<dim3(M / 32, N / 32), 256, 0, stream>>>(
      weight, part, rowS, W1, b1, W2, b2, W3, b3, Wt);

  bquant_kernel<<<M, 256, 0, stream>>>(Wt, B1q, B2q, sw1);

  gemm_kernel<<<dim3(M / BN, Bdim / BM), 512, 0, stream>>>(
      X1, X2, B1q, B2q, sw1, out);

  softmax_kernel<<<Bdim / 4, 256, 0, stream>>>(out, sx1);
}